// Round 7
// baseline (13001.492 us; speedup 1.0000x reference)
//
#include <hip/hip_runtime.h>

namespace {

constexpr int NB = 16, HH = 128, WW = 128, KK = 512, DD = 128;
constexpr int NPIX = NB * HH * WW;        // 262144
constexpr int NELEM = NPIX * DD;          // 33554432
constexpr int XRECON = NB * 3 * HH * WW;  // 786432
constexpr int VQ_BLK_PX = 32;
constexpr int VQ_BLOCKS = NPIX / VQ_BLK_PX;  // 8192

// ---------- zero the code-usage histogram (lives in d_out scratch) ----------
__global__ void zero_counts(int* __restrict__ counts) {
  const int t = threadIdx.x;
  counts[t] = 0;
  counts[t + 256] = 0;
}

// ---------- direct 3x3 conv, stride1 pad1, NCHW ----------
// fp32 storage in/out (matches reference interlayer quantization), fp64 acc
// (order-noise 1e-16 -> value is the correctly-rounded center of any fp32
// implementation's noise cluster).
template <int CIN, int CT, bool TRANS, typename TIN, typename TOUT, typename ACC>
__global__ __launch_bounds__(256, 2) void conv3x3(
    const TIN* __restrict__ in, const float* __restrict__ w,
    const float* __restrict__ bias, TOUT* __restrict__ out) {
  __shared__ __align__(16) TIN s_in[CT][3][72];   // [ci][row][px]; px = x - x0base + 1
  __shared__ __align__(16) float s_w[CT * 9][132]; // [ci*9+tap][oc]
  const int tid = threadIdx.x;
  const int b = blockIdx.x >> 8;
  const int y = (blockIdx.x >> 1) & 127;
  const int x0base = (blockIdx.x & 1) << 6;
  const int ocg = tid >> 3;  // 32 groups of 4 oc
  const int pxg = tid & 7;   // 8 groups of 8 px
  const int x0 = pxg * 8;

  ACC acc[4][8];
#pragma unroll
  for (int k = 0; k < 4; ++k)
#pragma unroll
    for (int p = 0; p < 8; ++p) acc[k][p] = (ACC)0;

#pragma unroll 1
  for (int ci0 = 0; ci0 < CIN; ci0 += CT) {
    for (int i = tid; i < CT * 198; i += 256) {
      int ci = i / 198;
      int rem = i - ci * 198;
      int r = rem / 66;
      int px = rem - r * 66;
      int yy = y + r - 1;
      int xx = x0base + px - 1;
      TIN v = (TIN)0;
      if (yy >= 0 && yy < HH && xx >= 0 && xx < WW)
        v = in[((b * CIN + ci0 + ci) * HH + yy) * WW + xx];
      s_in[ci][r][px] = v;
    }
    for (int i = tid; i < 128 * CT * 9; i += 256) {
      int oc = i / (CT * 9);
      int j = i - oc * (CT * 9);
      float wv;
      if (!TRANS) {
        wv = w[oc * (CIN * 9) + ci0 * 9 + j];
      } else {
        int ci = j / 9;
        int tap = j - ci * 9;
        int ky = tap / 3, kx = tap - ky * 3;
        wv = w[((ci0 + ci) * 128 + oc) * 9 + (2 - ky) * 3 + (2 - kx)];
      }
      s_w[j][oc] = wv;
    }
    __syncthreads();
#pragma unroll 1
    for (int ci = 0; ci < CT; ++ci) {
#pragma unroll
      for (int r = 0; r < 3; ++r) {
        ACC ind[10];
#pragma unroll
        for (int m = 0; m < 10; ++m) ind[m] = (ACC)s_in[ci][r][x0 + m];
#pragma unroll
        for (int dx = 0; dx < 3; ++dx) {
          float4 w4 = *reinterpret_cast<const float4*>(&s_w[ci * 9 + r * 3 + dx][ocg * 4]);
          ACC wd[4] = {(ACC)w4.x, (ACC)w4.y, (ACC)w4.z, (ACC)w4.w};
#pragma unroll
          for (int k = 0; k < 4; ++k)
#pragma unroll
            for (int p = 0; p < 8; ++p) acc[k][p] += wd[k] * ind[p + dx];
        }
      }
    }
    __syncthreads();
  }
#pragma unroll
  for (int k = 0; k < 4; ++k) {
    int oc = ocg * 4 + k;
    ACC bv = (ACC)bias[oc];
    TOUT* op = out + ((b * 128 + oc) * HH + y) * WW + x0base + x0;
#pragma unroll
    for (int p = 0; p < 8; ++p) op[p] = (TOUT)(acc[k][p] + bv);
  }
}

// ---------- 1x1 conv (pre-VQ), fp32 NCHW -> fp32 NHWC flat, fp64 acc ----------
__global__ __launch_bounds__(256, 2) void prevq_nhwc(
    const float* __restrict__ in, const float* __restrict__ wmat,
    const float* __restrict__ bias, float* __restrict__ flat) {
  __shared__ __align__(16) float s_z[32][68];   // [c][px]
  __shared__ __align__(16) float s_w[32][132];  // [c][o]
  const int tid = threadIdx.x;
  const int b = blockIdx.x >> 8;
  const int y = (blockIdx.x >> 1) & 127;
  const int x0base = (blockIdx.x & 1) << 6;
  const int ocg = tid >> 3;  // 32 x 4 oc
  const int pxg = tid & 7;   // 8 x 8 px
  double acc[4][8];
#pragma unroll
  for (int k = 0; k < 4; ++k)
#pragma unroll
    for (int p = 0; p < 8; ++p) acc[k][p] = 0.0;

#pragma unroll 1
  for (int c0 = 0; c0 < 128; c0 += 32) {
    for (int t = tid; t < 32 * 64; t += 256) {
      int c = t >> 6, px = t & 63;
      s_z[c][px] = in[((b * 128 + c0 + c) * HH + y) * WW + x0base + px];
    }
    for (int t = tid; t < 32 * 128; t += 256) {
      int o = t >> 5, c = t & 31;
      s_w[c][o] = wmat[o * 128 + c0 + c];
    }
    __syncthreads();
#pragma unroll 1
    for (int c = 0; c < 32; ++c) {
      double f8[8];
#pragma unroll
      for (int p = 0; p < 8; ++p) f8[p] = (double)s_z[c][pxg * 8 + p];
      float4 w4 = *reinterpret_cast<const float4*>(&s_w[c][ocg * 4]);
      double wd[4] = {(double)w4.x, (double)w4.y, (double)w4.z, (double)w4.w};
#pragma unroll
      for (int k = 0; k < 4; ++k)
#pragma unroll
        for (int p = 0; p < 8; ++p) acc[k][p] += wd[k] * f8[p];
    }
    __syncthreads();
  }
  double bv[4];
#pragma unroll
  for (int k = 0; k < 4; ++k) bv[k] = (double)bias[ocg * 4 + k];
  const int pixbase = (b * HH + y) * WW + x0base + pxg * 8;
#pragma unroll
  for (int p = 0; p < 8; ++p) {
    float* op = flat + (pixbase + p) * DD + ocg * 4;
#pragma unroll
    for (int k = 0; k < 4; ++k) op[k] = (float)(acc[k][p] + bv[k]);
  }
}

// ---------- numpy-faithful fp32 sum of squares over 128 elems ----------
// numpy pairwise_sum n=128: 8 accumulators, unrolled-by-8, tree combine.
__device__ __forceinline__ float pairwise8_sq(const float* v) {
  float r[8];
#pragma unroll
  for (int j = 0; j < 8; ++j) r[j] = __fmul_rn(v[j], v[j]);
#pragma unroll
  for (int i = 8; i < 128; i += 8)
#pragma unroll
    for (int j = 0; j < 8; ++j) r[j] = __fadd_rn(r[j], __fmul_rn(v[i + j], v[i + j]));
  return __fadd_rn(__fadd_rn(__fadd_rn(r[0], r[1]), __fadd_rn(r[2], r[3])),
                   __fadd_rn(__fadd_rn(r[4], r[5]), __fadd_rn(r[6], r[7])));
}

// ---------- fused VQ, reference-faithful fp32 scoring on fp32-cluster z ----------
// G = fp32 K-ascending FMA chain (BLAS sgemm microkernel order);
// score = fp32( fp32(zn + en) - fp32(2*G) ); first-min tie-break == np.argmin.
__global__ __launch_bounds__(256, 2) void vq_fused(
    const float* __restrict__ flat, const float* __restrict__ codebook,
    float* __restrict__ q, float* __restrict__ partial, int* __restrict__ counts) {
  __shared__ __align__(16) float s_f[VQ_BLK_PX][132];
  __shared__ __align__(16) float s_c[32][132];
  __shared__ float s_cn[32];
  __shared__ float s_zn[VQ_BLK_PX];
  __shared__ float s_rb[VQ_BLK_PX][9];
  __shared__ int s_ri[VQ_BLK_PX][9];
  __shared__ int s_idx[VQ_BLK_PX];
  __shared__ double s_red[4];
  const int tid = threadIdx.x;
  const int n0 = blockIdx.x * VQ_BLK_PX;
  const int px = tid & 31;
  const int cg = tid >> 5;  // 8 code groups of 4

  for (int t = tid; t < VQ_BLK_PX * 128; t += 256) {
    int i = t >> 7, d = t & 127;
    s_f[i][d] = flat[(n0 + i) * DD + d];
  }
  __syncthreads();
  if (tid < VQ_BLK_PX) s_zn[tid] = pairwise8_sq(&s_f[tid][0]);

  float best = 3.402823466e+38f;
  int bi = 0;

#pragma unroll 1
  for (int c0 = 0; c0 < KK; c0 += 32) {
    for (int t = tid; t < 32 * 128; t += 256) {
      int cc = t >> 7, d = t & 127;
      s_c[cc][d] = codebook[(c0 + cc) * DD + d];
    }
    __syncthreads();
    if (tid < 32) s_cn[tid] = pairwise8_sq(&s_c[tid][0]);
    __syncthreads();
    float acc4[4] = {0.f, 0.f, 0.f, 0.f};
#pragma unroll 2
    for (int d = 0; d < 128; ++d) {
      float f = s_f[px][d];
#pragma unroll
      for (int j = 0; j < 4; ++j)
        acc4[j] = __fmaf_rn(f, s_c[cg * 4 + j][d], acc4[j]);
    }
#pragma unroll
    for (int j = 0; j < 4; ++j) {
      float score = __fsub_rn(__fadd_rn(s_zn[px], s_cn[cg * 4 + j]),
                              __fmul_rn(2.0f, acc4[j]));
      int code = c0 + cg * 4 + j;
      if (score < best) { best = score; bi = code; }
    }
    __syncthreads();
  }
  s_rb[px][cg] = best;
  s_ri[px][cg] = bi;
  __syncthreads();
  if (tid < 32) {
    float m = s_rb[tid][0];
    int mi = s_ri[tid][0];
    for (int g = 1; g < 8; ++g) {
      float v = s_rb[tid][g];
      int vi = s_ri[tid][g];
      if (v < m || (v == m && vi < mi)) { m = v; mi = vi; }
    }
    s_idx[tid] = mi;
  }
  __syncthreads();
  if (tid < 32) atomicAdd(&counts[s_idx[tid]], 1);

  // gather -> q (fp32 NCHW) + fp64 SSE vs fp32 z (still in s_f)
  const int dg = cg;  // 8 groups of 16 channels
  const int n = n0 + px;
  const int bl = n >> 14, rem = n & 16383, y = rem >> 7, x = rem & 127;
  const int k = s_idx[px];
  const float* crow = codebook + k * DD + dg * 16;
  float* qb = q + ((bl * 128 + dg * 16) * HH + y) * WW + x;
  double s = 0.0;
#pragma unroll 4
  for (int j = 0; j < 16; ++j) {
    float e = crow[j];
    double dd = (double)e - (double)s_f[px][dg * 16 + j];
    s += dd * dd;
    qb[j * (HH * WW)] = e;
  }
  for (int off = 32; off; off >>= 1) s += __shfl_down(s, off);
  if ((tid & 63) == 0) s_red[tid >> 6] = s;
  __syncthreads();
  if (tid == 0)
    partial[blockIdx.x] = (float)(s_red[0] + s_red[1] + s_red[2] + s_red[3]);
}

// ---------- final conv-transpose 128 -> 3, write x_recon (fp32) ----------
__global__ __launch_bounds__(128, 2) void conv_out3(
    const float* __restrict__ in, const float* __restrict__ w,
    const float* __restrict__ bias, float* __restrict__ out) {
  __shared__ float s_in[16][3][130];
  __shared__ float s_w[128][28];  // [ci][tap*3+oc]
  const int tid = threadIdx.x;  // 128
  const int b = blockIdx.x >> 7;
  const int y = blockIdx.x & 127;
  for (int i = tid; i < 128 * 27; i += 128) {
    int ci = i / 27, rem = i % 27, oc = rem / 9, tap = rem % 9;
    int ky = tap / 3, kx = tap % 3;
    s_w[ci][tap * 3 + oc] = w[((ci * 3 + oc) * 3 + (2 - ky)) * 3 + (2 - kx)];
  }
  double acc[3] = {0.0, 0.0, 0.0};
  const int x = tid;
#pragma unroll 1
  for (int ci0 = 0; ci0 < 128; ci0 += 16) {
    for (int i = tid; i < 16 * 390; i += 128) {
      int ci = i / 390;
      int rem = i - ci * 390;
      int r = rem / 130;
      int px = rem - r * 130;
      int yy = y + r - 1;
      float v = 0.f;
      if (yy >= 0 && yy < HH && px >= 1 && px <= 128)
        v = in[((b * 128 + ci0 + ci) * HH + yy) * WW + (px - 1)];
      s_in[ci][r][px] = v;
    }
    __syncthreads();
#pragma unroll 1
    for (int ci = 0; ci < 16; ++ci) {
#pragma unroll
      for (int r = 0; r < 3; ++r) {
        float i3[3] = {s_in[ci][r][x], s_in[ci][r][x + 1], s_in[ci][r][x + 2]};
#pragma unroll
        for (int dx = 0; dx < 3; ++dx)
#pragma unroll
          for (int oc = 0; oc < 3; ++oc)
            acc[oc] += (double)s_w[ci0 + ci][(r * 3 + dx) * 3 + oc] * (double)i3[dx];
      }
    }
    __syncthreads();
  }
#pragma unroll
  for (int oc = 0; oc < 3; ++oc)
    out[((b * 3 + oc) * HH + y) * WW + x] = (float)(acc[oc] + (double)bias[oc]);
}

// ---------- finalize: loss + perplexity (fp64; runs before decoder) ----------
__global__ void finalize(const float* __restrict__ partial,
                         const int* __restrict__ counts, float* __restrict__ out) {
  __shared__ double redh[4], reds[4];
  const int tid = threadIdx.x;  // 256
  double h = 0.0;
  for (int k = tid; k < KK; k += 256) {
    double p = (double)counts[k] * (1.0 / (double)NPIX);
    h += p * log(p + 1e-10);
  }
  double s = 0.0;
  for (int i = tid; i < VQ_BLOCKS; i += 256) s += (double)partial[i];
  for (int off = 32; off; off >>= 1) {
    h += __shfl_down(h, off);
    s += __shfl_down(s, off);
  }
  if ((tid & 63) == 0) { redh[tid >> 6] = h; reds[tid >> 6] = s; }
  __syncthreads();
  if (tid == 0) {
    double Hs = redh[0] + redh[1] + redh[2] + redh[3];
    double Ss = reds[0] + reds[1] + reds[2] + reds[3];
    out[0] = (float)(0.25 * Ss * (1.0 / (double)NELEM));
    out[1 + XRECON] = (float)exp(-Hs);
  }
}

}  // namespace

extern "C" void kernel_launch(void* const* d_in, const int* in_sizes, int n_in,
                              void* d_out, int out_size, void* d_ws, size_t ws_size,
                              hipStream_t stream) {
  (void)in_sizes; (void)n_in; (void)out_size; (void)ws_size;
  const float* x       = (const float*)d_in[0];
  const float* enc_w0  = (const float*)d_in[1];
  const float* enc_b0  = (const float*)d_in[2];
  const float* enc_wh  = (const float*)d_in[3];
  const float* enc_bh  = (const float*)d_in[4];
  const float* pre_w   = (const float*)d_in[5];
  const float* pre_b   = (const float*)d_in[6];
  const float* codebook= (const float*)d_in[7];
  const float* dec_wh  = (const float*)d_in[8];
  const float* dec_bh  = (const float*)d_in[9];
  const float* dec_wl  = (const float*)d_in[10];
  const float* dec_bl  = (const float*)d_in[11];
  float* out = (float*)d_out;

  // Workspace: exactly two NELEM fp32 activation buffers (256 MiB).
  float* A = (float*)d_ws;
  float* Bf = A + NELEM;
  // Transient scratch in d_out's x_recon region; consumed by finalize()
  // BEFORE the decoder writes d_out (stream-ordered).
  int* counts = (int*)(out + 1);  // 512 ints
  float* partial = out + 1 + KK;  // VQ_BLOCKS floats (8192)

  const int LSTRIDE = 128 * 128 * 9;  // per-layer weight stride
  const int CGRID = NB * HH * 2;      // 4096

  zero_counts<<<1, 256, 0, stream>>>(counts);

  // encoder: fp64 acc, fp32 interlayer storage (reference-matching quantization)
  conv3x3<3, 3, false, float, float, double><<<CGRID, 256, 0, stream>>>(
      x, enc_w0, enc_b0, A);
  conv3x3<128, 8, false, float, float, double><<<CGRID, 256, 0, stream>>>(
      A, enc_wh, enc_bh, Bf);
  conv3x3<128, 8, false, float, float, double><<<CGRID, 256, 0, stream>>>(
      Bf, enc_wh + LSTRIDE, enc_bh + 128, A);
  conv3x3<128, 8, false, float, float, double><<<CGRID, 256, 0, stream>>>(
      A, enc_wh + 2 * LSTRIDE, enc_bh + 256, Bf);

  // pre-VQ 1x1 -> fp32 NHWC flat in A (fp64 acc, one fp32 rounding)
  prevq_nhwc<<<CGRID, 256, 0, stream>>>(Bf, pre_w, pre_b, A);

  // VQ: fp32 BLAS-order FMA-chain scores (max correlation with jax/np); q -> Bf
  vq_fused<<<VQ_BLOCKS, 256, 0, stream>>>(A, codebook, Bf, partial, counts);

  // loss + perplexity (before decoder overwrites the d_out scratch region)
  finalize<<<1, 256, 0, stream>>>(partial, counts, out);

  // decoder: fp64 acc, fp32 storage
  conv3x3<128, 8, true, float, float, double><<<CGRID, 256, 0, stream>>>(
      Bf, dec_wh, dec_bh, A);
  conv3x3<128, 8, true, float, float, double><<<CGRID, 256, 0, stream>>>(
      A, dec_wh + LSTRIDE, dec_bh + 128, Bf);
  conv3x3<128, 8, true, float, float, double><<<CGRID, 256, 0, stream>>>(
      Bf, dec_wh + 2 * LSTRIDE, dec_bh + 256, A);
  conv_out3<<<NB * HH, 128, 0, stream>>>(A, dec_wl, dec_bl, out + 1);
}

// Round 8
// 10777.848 us; speedup vs baseline: 1.2063x; 1.2063x over previous
//
#include <hip/hip_runtime.h>

namespace {

constexpr int NB = 16, HH = 128, WW = 128, KK = 512, DD = 128;
constexpr int NPIX = NB * HH * WW;        // 262144
constexpr int NELEM = NPIX * DD;          // 33554432
constexpr int XRECON = NB * 3 * HH * WW;  // 786432
constexpr int VQ_BLK_PX = 32;
constexpr int VQ_BLOCKS = NPIX / VQ_BLK_PX;  // 8192

// ---------- zero the code-usage histogram (lives in d_out scratch) ----------
__global__ void zero_counts(int* __restrict__ counts) {
  const int t = threadIdx.x;
  counts[t] = 0;
  counts[t + 256] = 0;
}

// ---------- direct 3x3 conv, stride1 pad1, NCHW ----------
// fp32 storage in/out; ACC=double for encoder (correctly-rounded z cluster
// center), ACC=float for decoder (noise << bf16 quantum of the check).
// s_in is stored PRE-WIDENED to ACC (cvt once at stage, not per-FMA) and
// bank-swizzled: phys = px + (px>>3) -> 8 wave-distinct read addrs hit 8
// distinct banks (conflict-free for both 4B and 8B elements).
template <int CIN, int CT, bool TRANS, typename TIN, typename TOUT, typename ACC>
__global__ __launch_bounds__(256, 3) void conv3x3(
    const TIN* __restrict__ in, const float* __restrict__ w,
    const float* __restrict__ bias, TOUT* __restrict__ out) {
  __shared__ __align__(16) ACC s_in[CT][3][74];    // [ci][row][phys(px)]
  __shared__ __align__(16) float s_w[CT * 9][132]; // [ci*9+tap][oc]
  const int tid = threadIdx.x;
  const int b = blockIdx.x >> 8;
  const int y = (blockIdx.x >> 1) & 127;
  const int x0base = (blockIdx.x & 1) << 6;
  const int ocg = tid >> 3;  // 32 groups of 4 oc
  const int pxg = tid & 7;   // 8 groups of 8 px
  const int x0 = pxg * 8;
  const int f0 = pxg * 9;    // swizzled base: px=pxg*8 -> phys=pxg*9

  ACC acc[4][8];
#pragma unroll
  for (int k = 0; k < 4; ++k)
#pragma unroll
    for (int p = 0; p < 8; ++p) acc[k][p] = (ACC)0;

#pragma unroll 1
  for (int ci0 = 0; ci0 < CIN; ci0 += CT) {
    for (int i = tid; i < CT * 198; i += 256) {
      int ci = i / 198;
      int rem = i - ci * 198;
      int r = rem / 66;
      int px = rem - r * 66;
      int yy = y + r - 1;
      int xx = x0base + px - 1;
      TIN v = (TIN)0;
      if (yy >= 0 && yy < HH && xx >= 0 && xx < WW)
        v = in[((b * CIN + ci0 + ci) * HH + yy) * WW + xx];
      s_in[ci][r][px + (px >> 3)] = (ACC)v;
    }
    for (int i = tid; i < 128 * CT * 9; i += 256) {
      int oc = i / (CT * 9);
      int j = i - oc * (CT * 9);
      float wv;
      if (!TRANS) {
        wv = w[oc * (CIN * 9) + ci0 * 9 + j];
      } else {
        int ci = j / 9;
        int tap = j - ci * 9;
        int ky = tap / 3, kx = tap - ky * 3;
        wv = w[((ci0 + ci) * 128 + oc) * 9 + (2 - ky) * 3 + (2 - kx)];
      }
      s_w[j][oc] = wv;
    }
    __syncthreads();
#pragma unroll 1
    for (int ci = 0; ci < CT; ++ci) {
#pragma unroll
      for (int r = 0; r < 3; ++r) {
        ACC ind[10];
#pragma unroll
        for (int m = 0; m < 8; ++m) ind[m] = s_in[ci][r][f0 + m];
        ind[8] = s_in[ci][r][f0 + 9];   // px = x0+8 -> phys f0+9
        ind[9] = s_in[ci][r][f0 + 10];  // px = x0+9 -> phys f0+10
#pragma unroll
        for (int dx = 0; dx < 3; ++dx) {
          float4 w4 = *reinterpret_cast<const float4*>(&s_w[ci * 9 + r * 3 + dx][ocg * 4]);
          ACC wd[4] = {(ACC)w4.x, (ACC)w4.y, (ACC)w4.z, (ACC)w4.w};
#pragma unroll
          for (int k = 0; k < 4; ++k)
#pragma unroll
            for (int p = 0; p < 8; ++p) acc[k][p] += wd[k] * ind[p + dx];
        }
      }
    }
    __syncthreads();
  }
#pragma unroll
  for (int k = 0; k < 4; ++k) {
    int oc = ocg * 4 + k;
    ACC bv = (ACC)bias[oc];
    TOUT* op = out + ((b * 128 + oc) * HH + y) * WW + x0base + x0;
#pragma unroll
    for (int p = 0; p < 8; ++p) op[p] = (TOUT)(acc[k][p] + bv);
  }
}

// ---------- 1x1 conv (pre-VQ), fp32 NCHW -> fp32 NHWC flat, fp64 acc ----------
__global__ __launch_bounds__(256, 3) void prevq_nhwc(
    const float* __restrict__ in, const float* __restrict__ wmat,
    const float* __restrict__ bias, float* __restrict__ flat) {
  __shared__ __align__(16) float s_z[32][68];   // [c][px]
  __shared__ __align__(16) float s_w[32][132];  // [c][o]
  const int tid = threadIdx.x;
  const int b = blockIdx.x >> 8;
  const int y = (blockIdx.x >> 1) & 127;
  const int x0base = (blockIdx.x & 1) << 6;
  const int ocg = tid >> 3;  // 32 x 4 oc
  const int pxg = tid & 7;   // 8 x 8 px
  double acc[4][8];
#pragma unroll
  for (int k = 0; k < 4; ++k)
#pragma unroll
    for (int p = 0; p < 8; ++p) acc[k][p] = 0.0;

#pragma unroll 1
  for (int c0 = 0; c0 < 128; c0 += 32) {
    for (int t = tid; t < 32 * 64; t += 256) {
      int c = t >> 6, px = t & 63;
      s_z[c][px] = in[((b * 128 + c0 + c) * HH + y) * WW + x0base + px];
    }
    for (int t = tid; t < 32 * 128; t += 256) {
      int o = t >> 5, c = t & 31;
      s_w[c][o] = wmat[o * 128 + c0 + c];
    }
    __syncthreads();
#pragma unroll 1
    for (int c = 0; c < 32; ++c) {
      double f8[8];
#pragma unroll
      for (int p = 0; p < 8; ++p) f8[p] = (double)s_z[c][pxg * 8 + p];
      float4 w4 = *reinterpret_cast<const float4*>(&s_w[c][ocg * 4]);
      double wd[4] = {(double)w4.x, (double)w4.y, (double)w4.z, (double)w4.w};
#pragma unroll
      for (int k = 0; k < 4; ++k)
#pragma unroll
        for (int p = 0; p < 8; ++p) acc[k][p] += wd[k] * f8[p];
    }
    __syncthreads();
  }
  double bv[4];
#pragma unroll
  for (int k = 0; k < 4; ++k) bv[k] = (double)bias[ocg * 4 + k];
  const int pixbase = (b * HH + y) * WW + x0base + pxg * 8;
#pragma unroll
  for (int p = 0; p < 8; ++p) {
    float* op = flat + (pixbase + p) * DD + ocg * 4;
#pragma unroll
    for (int k = 0; k < 4; ++k) op[k] = (float)(acc[k][p] + bv[k]);
  }
}

// ---------- numpy-faithful fp32 sum of squares over 128 elems ----------
__device__ __forceinline__ float pairwise8_sq(const float* v) {
  float r[8];
#pragma unroll
  for (int j = 0; j < 8; ++j) r[j] = __fmul_rn(v[j], v[j]);
#pragma unroll
  for (int i = 8; i < 128; i += 8)
#pragma unroll
    for (int j = 0; j < 8; ++j) r[j] = __fadd_rn(r[j], __fmul_rn(v[i + j], v[i + j]));
  return __fadd_rn(__fadd_rn(__fadd_rn(r[0], r[1]), __fadd_rn(r[2], r[3])),
                   __fadd_rn(__fadd_rn(r[4], r[5]), __fadd_rn(r[6], r[7])));
}

// ---------- fused VQ, reference-faithful fp32 scoring (DO NOT CHANGE MATH) ----------
__global__ __launch_bounds__(256, 2) void vq_fused(
    const float* __restrict__ flat, const float* __restrict__ codebook,
    float* __restrict__ q, float* __restrict__ partial, int* __restrict__ counts) {
  __shared__ __align__(16) float s_f[VQ_BLK_PX][132];
  __shared__ __align__(16) float s_c[32][132];
  __shared__ float s_cn[32];
  __shared__ float s_zn[VQ_BLK_PX];
  __shared__ float s_rb[VQ_BLK_PX][9];
  __shared__ int s_ri[VQ_BLK_PX][9];
  __shared__ int s_idx[VQ_BLK_PX];
  __shared__ double s_red[4];
  const int tid = threadIdx.x;
  const int n0 = blockIdx.x * VQ_BLK_PX;
  const int px = tid & 31;
  const int cg = tid >> 5;  // 8 code groups of 4

  for (int t = tid; t < VQ_BLK_PX * 128; t += 256) {
    int i = t >> 7, d = t & 127;
    s_f[i][d] = flat[(n0 + i) * DD + d];
  }
  __syncthreads();
  if (tid < VQ_BLK_PX) s_zn[tid] = pairwise8_sq(&s_f[tid][0]);

  float best = 3.402823466e+38f;
  int bi = 0;

#pragma unroll 1
  for (int c0 = 0; c0 < KK; c0 += 32) {
    for (int t = tid; t < 32 * 128; t += 256) {
      int cc = t >> 7, d = t & 127;
      s_c[cc][d] = codebook[(c0 + cc) * DD + d];
    }
    __syncthreads();
    if (tid < 32) s_cn[tid] = pairwise8_sq(&s_c[tid][0]);
    __syncthreads();
    float acc4[4] = {0.f, 0.f, 0.f, 0.f};
#pragma unroll 2
    for (int d = 0; d < 128; ++d) {
      float f = s_f[px][d];
#pragma unroll
      for (int j = 0; j < 4; ++j)
        acc4[j] = __fmaf_rn(f, s_c[cg * 4 + j][d], acc4[j]);
    }
#pragma unroll
    for (int j = 0; j < 4; ++j) {
      float score = __fsub_rn(__fadd_rn(s_zn[px], s_cn[cg * 4 + j]),
                              __fmul_rn(2.0f, acc4[j]));
      int code = c0 + cg * 4 + j;
      if (score < best) { best = score; bi = code; }
    }
    __syncthreads();
  }
  s_rb[px][cg] = best;
  s_ri[px][cg] = bi;
  __syncthreads();
  if (tid < 32) {
    float m = s_rb[tid][0];
    int mi = s_ri[tid][0];
    for (int g = 1; g < 8; ++g) {
      float v = s_rb[tid][g];
      int vi = s_ri[tid][g];
      if (v < m || (v == m && vi < mi)) { m = v; mi = vi; }
    }
    s_idx[tid] = mi;
  }
  __syncthreads();
  if (tid < 32) atomicAdd(&counts[s_idx[tid]], 1);

  // gather -> q (fp32 NCHW) + fp64 SSE vs fp32 z (still in s_f)
  const int dg = cg;  // 8 groups of 16 channels
  const int n = n0 + px;
  const int bl = n >> 14, rem = n & 16383, y = rem >> 7, x = rem & 127;
  const int k = s_idx[px];
  const float* crow = codebook + k * DD + dg * 16;
  float* qb = q + ((bl * 128 + dg * 16) * HH + y) * WW + x;
  double s = 0.0;
#pragma unroll 4
  for (int j = 0; j < 16; ++j) {
    float e = crow[j];
    double dd = (double)e - (double)s_f[px][dg * 16 + j];
    s += dd * dd;
    qb[j * (HH * WW)] = e;
  }
  for (int off = 32; off; off >>= 1) s += __shfl_down(s, off);
  if ((tid & 63) == 0) s_red[tid >> 6] = s;
  __syncthreads();
  if (tid == 0)
    partial[blockIdx.x] = (float)(s_red[0] + s_red[1] + s_red[2] + s_red[3]);
}

// ---------- final conv-transpose 128 -> 3, write x_recon ----------
__global__ __launch_bounds__(128, 2) void conv_out3(
    const float* __restrict__ in, const float* __restrict__ w,
    const float* __restrict__ bias, float* __restrict__ out) {
  __shared__ float s_in[16][3][130];
  __shared__ float s_w[128][28];  // [ci][tap*3+oc]
  const int tid = threadIdx.x;  // 128
  const int b = blockIdx.x >> 7;
  const int y = blockIdx.x & 127;
  for (int i = tid; i < 128 * 27; i += 128) {
    int ci = i / 27, rem = i % 27, oc = rem / 9, tap = rem % 9;
    int ky = tap / 3, kx = tap % 3;
    s_w[ci][tap * 3 + oc] = w[((ci * 3 + oc) * 3 + (2 - ky)) * 3 + (2 - kx)];
  }
  float acc[3] = {0.f, 0.f, 0.f};
  const int x = tid;
#pragma unroll 1
  for (int ci0 = 0; ci0 < 128; ci0 += 16) {
    for (int i = tid; i < 16 * 390; i += 128) {
      int ci = i / 390;
      int rem = i - ci * 390;
      int r = rem / 130;
      int px = rem - r * 130;
      int yy = y + r - 1;
      float v = 0.f;
      if (yy >= 0 && yy < HH && px >= 1 && px <= 128)
        v = in[((b * 128 + ci0 + ci) * HH + yy) * WW + (px - 1)];
      s_in[ci][r][px] = v;
    }
    __syncthreads();
#pragma unroll 1
    for (int ci = 0; ci < 16; ++ci) {
#pragma unroll
      for (int r = 0; r < 3; ++r) {
        float i3[3] = {s_in[ci][r][x], s_in[ci][r][x + 1], s_in[ci][r][x + 2]};
#pragma unroll
        for (int dx = 0; dx < 3; ++dx)
#pragma unroll
          for (int oc = 0; oc < 3; ++oc)
            acc[oc] += s_w[ci0 + ci][(r * 3 + dx) * 3 + oc] * i3[dx];
      }
    }
    __syncthreads();
  }
#pragma unroll
  for (int oc = 0; oc < 3; ++oc)
    out[((b * 3 + oc) * HH + y) * WW + x] = acc[oc] + bias[oc];
}

// ---------- finalize: loss + perplexity (fp64; runs before decoder) ----------
__global__ void finalize(const float* __restrict__ partial,
                         const int* __restrict__ counts, float* __restrict__ out) {
  __shared__ double redh[4], reds[4];
  const int tid = threadIdx.x;  // 256
  double h = 0.0;
  for (int k = tid; k < KK; k += 256) {
    double p = (double)counts[k] * (1.0 / (double)NPIX);
    h += p * log(p + 1e-10);
  }
  double s = 0.0;
  for (int i = tid; i < VQ_BLOCKS; i += 256) s += (double)partial[i];
  for (int off = 32; off; off >>= 1) {
    h += __shfl_down(h, off);
    s += __shfl_down(s, off);
  }
  if ((tid & 63) == 0) { redh[tid >> 6] = h; reds[tid >> 6] = s; }
  __syncthreads();
  if (tid == 0) {
    double Hs = redh[0] + redh[1] + redh[2] + redh[3];
    double Ss = reds[0] + reds[1] + reds[2] + reds[3];
    out[0] = (float)(0.25 * Ss * (1.0 / (double)NELEM));
    out[1 + XRECON] = (float)exp(-Hs);
  }
}

}  // namespace

extern "C" void kernel_launch(void* const* d_in, const int* in_sizes, int n_in,
                              void* d_out, int out_size, void* d_ws, size_t ws_size,
                              hipStream_t stream) {
  (void)in_sizes; (void)n_in; (void)out_size; (void)ws_size;
  const float* x       = (const float*)d_in[0];
  const float* enc_w0  = (const float*)d_in[1];
  const float* enc_b0  = (const float*)d_in[2];
  const float* enc_wh  = (const float*)d_in[3];
  const float* enc_bh  = (const float*)d_in[4];
  const float* pre_w   = (const float*)d_in[5];
  const float* pre_b   = (const float*)d_in[6];
  const float* codebook= (const float*)d_in[7];
  const float* dec_wh  = (const float*)d_in[8];
  const float* dec_bh  = (const float*)d_in[9];
  const float* dec_wl  = (const float*)d_in[10];
  const float* dec_bl  = (const float*)d_in[11];
  float* out = (float*)d_out;

  // Workspace: exactly two NELEM fp32 activation buffers (256 MiB).
  float* A = (float*)d_ws;
  float* Bf = A + NELEM;
  // Transient scratch in d_out's x_recon region; consumed by finalize()
  // BEFORE the decoder writes d_out (stream-ordered).
  int* counts = (int*)(out + 1);  // 512 ints
  float* partial = out + 1 + KK;  // VQ_BLOCKS floats (8192)

  const int LSTRIDE = 128 * 128 * 9;  // per-layer weight stride
  const int CGRID = NB * HH * 2;      // 4096

  zero_counts<<<1, 256, 0, stream>>>(counts);

  // encoder: fp64 acc, fp32 interlayer storage (reference-matching quantization)
  conv3x3<3, 3, false, float, float, double><<<CGRID, 256, 0, stream>>>(
      x, enc_w0, enc_b0, A);
  conv3x3<128, 8, false, float, float, double><<<CGRID, 256, 0, stream>>>(
      A, enc_wh, enc_bh, Bf);
  conv3x3<128, 8, false, float, float, double><<<CGRID, 256, 0, stream>>>(
      Bf, enc_wh + LSTRIDE, enc_bh + 128, A);
  conv3x3<128, 8, false, float, float, double><<<CGRID, 256, 0, stream>>>(
      A, enc_wh + 2 * LSTRIDE, enc_bh + 256, Bf);

  // pre-VQ 1x1 -> fp32 NHWC flat in A (fp64 acc, one fp32 rounding)
  prevq_nhwc<<<CGRID, 256, 0, stream>>>(Bf, pre_w, pre_b, A);

  // VQ: fp32 BLAS-order FMA-chain scores (verified correct r7); q -> Bf
  vq_fused<<<VQ_BLOCKS, 256, 0, stream>>>(A, codebook, Bf, partial, counts);

  // loss + perplexity (before decoder overwrites the d_out scratch region)
  finalize<<<1, 256, 0, stream>>>(partial, counts, out);

  // decoder: fp32 acc (noise << bf16 quantum of the check; r2 evidence)
  conv3x3<128, 8, true, float, float, float><<<CGRID, 256, 0, stream>>>(
      Bf, dec_wh, dec_bh, A);
  conv3x3<128, 8, true, float, float, float><<<CGRID, 256, 0, stream>>>(
      A, dec_wh + LSTRIDE, dec_bh + 128, Bf);
  conv3x3<128, 8, true, float, float, float><<<CGRID, 256, 0, stream>>>(
      Bf, dec_wh + 2 * LSTRIDE, dec_bh + 256, A);
  conv_out3<<<NB * HH, 128, 0, stream>>>(A, dec_wl, dec_bl, out + 1);
}

// Round 9
// 9122.028 us; speedup vs baseline: 1.4253x; 1.1815x over previous
//
#include <hip/hip_runtime.h>

namespace {

constexpr int NB = 16, HH = 128, WW = 128, KK = 512, DD = 128;
constexpr int NPIX = NB * HH * WW;        // 262144
constexpr int NELEM = NPIX * DD;          // 33554432
constexpr int XRECON = NB * 3 * HH * WW;  // 786432
constexpr int VQ_BLK_PX = 32;
constexpr int VQ_BLOCKS = NPIX / VQ_BLK_PX;  // 8192

// ---------- zero the code-usage histogram (lives in d_out scratch) ----------
__global__ void zero_counts(int* __restrict__ counts) {
  const int t = threadIdx.x;
  counts[t] = 0;
  counts[t + 256] = 0;
}

// ---------- direct 3x3 conv, stride1 pad1, NCHW ----------
// fp32 storage in/out. ACC=float for the 128->128 encoder convs (fp32
// K-sequential order = faithful sample of the reference fp32 cluster;
// r9 experiment) and decoder; ACC=double for layer-1 conv (cheap).
// s_in pre-widened to ACC at stage time; bank-swizzle phys = px + (px>>3).
template <int CIN, int CT, bool TRANS, typename TIN, typename TOUT, typename ACC>
__global__ __launch_bounds__(256, 3) void conv3x3(
    const TIN* __restrict__ in, const float* __restrict__ w,
    const float* __restrict__ bias, TOUT* __restrict__ out) {
  __shared__ __align__(16) ACC s_in[CT][3][74];    // [ci][row][phys(px)]
  __shared__ __align__(16) float s_w[CT * 9][132]; // [ci*9+tap][oc]
  const int tid = threadIdx.x;
  const int b = blockIdx.x >> 8;
  const int y = (blockIdx.x >> 1) & 127;
  const int x0base = (blockIdx.x & 1) << 6;
  const int ocg = tid >> 3;  // 32 groups of 4 oc
  const int pxg = tid & 7;   // 8 groups of 8 px
  const int x0 = pxg * 8;
  const int f0 = pxg * 9;    // swizzled base: px=pxg*8 -> phys=pxg*9

  ACC acc[4][8];
#pragma unroll
  for (int k = 0; k < 4; ++k)
#pragma unroll
    for (int p = 0; p < 8; ++p) acc[k][p] = (ACC)0;

#pragma unroll 1
  for (int ci0 = 0; ci0 < CIN; ci0 += CT) {
    for (int i = tid; i < CT * 198; i += 256) {
      int ci = i / 198;
      int rem = i - ci * 198;
      int r = rem / 66;
      int px = rem - r * 66;
      int yy = y + r - 1;
      int xx = x0base + px - 1;
      TIN v = (TIN)0;
      if (yy >= 0 && yy < HH && xx >= 0 && xx < WW)
        v = in[((b * CIN + ci0 + ci) * HH + yy) * WW + xx];
      s_in[ci][r][px + (px >> 3)] = (ACC)v;
    }
    for (int i = tid; i < 128 * CT * 9; i += 256) {
      int oc = i / (CT * 9);
      int j = i - oc * (CT * 9);
      float wv;
      if (!TRANS) {
        wv = w[oc * (CIN * 9) + ci0 * 9 + j];
      } else {
        int ci = j / 9;
        int tap = j - ci * 9;
        int ky = tap / 3, kx = tap - ky * 3;
        wv = w[((ci0 + ci) * 128 + oc) * 9 + (2 - ky) * 3 + (2 - kx)];
      }
      s_w[j][oc] = wv;
    }
    __syncthreads();
#pragma unroll 1
    for (int ci = 0; ci < CT; ++ci) {
#pragma unroll
      for (int r = 0; r < 3; ++r) {
        ACC ind[10];
#pragma unroll
        for (int m = 0; m < 8; ++m) ind[m] = s_in[ci][r][f0 + m];
        ind[8] = s_in[ci][r][f0 + 9];   // px = x0+8 -> phys f0+9
        ind[9] = s_in[ci][r][f0 + 10];  // px = x0+9 -> phys f0+10
#pragma unroll
        for (int dx = 0; dx < 3; ++dx) {
          float4 w4 = *reinterpret_cast<const float4*>(&s_w[ci * 9 + r * 3 + dx][ocg * 4]);
          ACC wd[4] = {(ACC)w4.x, (ACC)w4.y, (ACC)w4.z, (ACC)w4.w};
#pragma unroll
          for (int k = 0; k < 4; ++k)
#pragma unroll
            for (int p = 0; p < 8; ++p) acc[k][p] += wd[k] * ind[p + dx];
        }
      }
    }
    __syncthreads();
  }
#pragma unroll
  for (int k = 0; k < 4; ++k) {
    int oc = ocg * 4 + k;
    ACC bv = (ACC)bias[oc];
    TOUT* op = out + ((b * 128 + oc) * HH + y) * WW + x0base + x0;
#pragma unroll
    for (int p = 0; p < 8; ++p) op[p] = (TOUT)(acc[k][p] + bv);
  }
}

// ---------- 1x1 conv (pre-VQ), fp32 NCHW -> fp32 NHWC flat, fp64 acc ----------
__global__ __launch_bounds__(256, 3) void prevq_nhwc(
    const float* __restrict__ in, const float* __restrict__ wmat,
    const float* __restrict__ bias, float* __restrict__ flat) {
  __shared__ __align__(16) float s_z[32][68];   // [c][px]
  __shared__ __align__(16) float s_w[32][132];  // [c][o]
  const int tid = threadIdx.x;
  const int b = blockIdx.x >> 8;
  const int y = (blockIdx.x >> 1) & 127;
  const int x0base = (blockIdx.x & 1) << 6;
  const int ocg = tid >> 3;  // 32 x 4 oc
  const int pxg = tid & 7;   // 8 x 8 px
  double acc[4][8];
#pragma unroll
  for (int k = 0; k < 4; ++k)
#pragma unroll
    for (int p = 0; p < 8; ++p) acc[k][p] = 0.0;

#pragma unroll 1
  for (int c0 = 0; c0 < 128; c0 += 32) {
    for (int t = tid; t < 32 * 64; t += 256) {
      int c = t >> 6, px = t & 63;
      s_z[c][px] = in[((b * 128 + c0 + c) * HH + y) * WW + x0base + px];
    }
    for (int t = tid; t < 32 * 128; t += 256) {
      int o = t >> 5, c = t & 31;
      s_w[c][o] = wmat[o * 128 + c0 + c];
    }
    __syncthreads();
#pragma unroll 1
    for (int c = 0; c < 32; ++c) {
      double f8[8];
#pragma unroll
      for (int p = 0; p < 8; ++p) f8[p] = (double)s_z[c][pxg * 8 + p];
      float4 w4 = *reinterpret_cast<const float4*>(&s_w[c][ocg * 4]);
      double wd[4] = {(double)w4.x, (double)w4.y, (double)w4.z, (double)w4.w};
#pragma unroll
      for (int k = 0; k < 4; ++k)
#pragma unroll
        for (int p = 0; p < 8; ++p) acc[k][p] += wd[k] * f8[p];
    }
    __syncthreads();
  }
  double bv[4];
#pragma unroll
  for (int k = 0; k < 4; ++k) bv[k] = (double)bias[ocg * 4 + k];
  const int pixbase = (b * HH + y) * WW + x0base + pxg * 8;
#pragma unroll
  for (int p = 0; p < 8; ++p) {
    float* op = flat + (pixbase + p) * DD + ocg * 4;
#pragma unroll
    for (int k = 0; k < 4; ++k) op[k] = (float)(acc[k][p] + bv[k]);
  }
}

// ---------- numpy-faithful fp32 sum of squares over 128 elems ----------
__device__ __forceinline__ float pairwise8_sq(const float* v) {
  float r[8];
#pragma unroll
  for (int j = 0; j < 8; ++j) r[j] = __fmul_rn(v[j], v[j]);
#pragma unroll
  for (int i = 8; i < 128; i += 8)
#pragma unroll
    for (int j = 0; j < 8; ++j) r[j] = __fadd_rn(r[j], __fmul_rn(v[i + j], v[i + j]));
  return __fadd_rn(__fadd_rn(__fadd_rn(r[0], r[1]), __fadd_rn(r[2], r[3])),
                   __fadd_rn(__fadd_rn(r[4], r[5]), __fadd_rn(r[6], r[7])));
}

// ---------- fused VQ, reference-faithful fp32 scoring (DO NOT CHANGE MATH) ----------
__global__ __launch_bounds__(256, 2) void vq_fused(
    const float* __restrict__ flat, const float* __restrict__ codebook,
    float* __restrict__ q, float* __restrict__ partial, int* __restrict__ counts) {
  __shared__ __align__(16) float s_f[VQ_BLK_PX][132];
  __shared__ __align__(16) float s_c[32][132];
  __shared__ float s_cn[32];
  __shared__ float s_zn[VQ_BLK_PX];
  __shared__ float s_rb[VQ_BLK_PX][9];
  __shared__ int s_ri[VQ_BLK_PX][9];
  __shared__ int s_idx[VQ_BLK_PX];
  __shared__ double s_red[4];
  const int tid = threadIdx.x;
  const int n0 = blockIdx.x * VQ_BLK_PX;
  const int px = tid & 31;
  const int cg = tid >> 5;  // 8 code groups of 4

  for (int t = tid; t < VQ_BLK_PX * 128; t += 256) {
    int i = t >> 7, d = t & 127;
    s_f[i][d] = flat[(n0 + i) * DD + d];
  }
  __syncthreads();
  if (tid < VQ_BLK_PX) s_zn[tid] = pairwise8_sq(&s_f[tid][0]);

  float best = 3.402823466e+38f;
  int bi = 0;

#pragma unroll 1
  for (int c0 = 0; c0 < KK; c0 += 32) {
    for (int t = tid; t < 32 * 128; t += 256) {
      int cc = t >> 7, d = t & 127;
      s_c[cc][d] = codebook[(c0 + cc) * DD + d];
    }
    __syncthreads();
    if (tid < 32) s_cn[tid] = pairwise8_sq(&s_c[tid][0]);
    __syncthreads();
    float acc4[4] = {0.f, 0.f, 0.f, 0.f};
#pragma unroll 2
    for (int d = 0; d < 128; ++d) {
      float f = s_f[px][d];
#pragma unroll
      for (int j = 0; j < 4; ++j)
        acc4[j] = __fmaf_rn(f, s_c[cg * 4 + j][d], acc4[j]);
    }
#pragma unroll
    for (int j = 0; j < 4; ++j) {
      float score = __fsub_rn(__fadd_rn(s_zn[px], s_cn[cg * 4 + j]),
                              __fmul_rn(2.0f, acc4[j]));
      int code = c0 + cg * 4 + j;
      if (score < best) { best = score; bi = code; }
    }
    __syncthreads();
  }
  s_rb[px][cg] = best;
  s_ri[px][cg] = bi;
  __syncthreads();
  if (tid < 32) {
    float m = s_rb[tid][0];
    int mi = s_ri[tid][0];
    for (int g = 1; g < 8; ++g) {
      float v = s_rb[tid][g];
      int vi = s_ri[tid][g];
      if (v < m || (v == m && vi < mi)) { m = v; mi = vi; }
    }
    s_idx[tid] = mi;
  }
  __syncthreads();
  if (tid < 32) atomicAdd(&counts[s_idx[tid]], 1);

  // gather -> q (fp32 NCHW) + fp64 SSE vs fp32 z (still in s_f)
  const int dg = cg;  // 8 groups of 16 channels
  const int n = n0 + px;
  const int bl = n >> 14, rem = n & 16383, y = rem >> 7, x = rem & 127;
  const int k = s_idx[px];
  const float* crow = codebook + k * DD + dg * 16;
  float* qb = q + ((bl * 128 + dg * 16) * HH + y) * WW + x;
  double s = 0.0;
#pragma unroll 4
  for (int j = 0; j < 16; ++j) {
    float e = crow[j];
    double dd = (double)e - (double)s_f[px][dg * 16 + j];
    s += dd * dd;
    qb[j * (HH * WW)] = e;
  }
  for (int off = 32; off; off >>= 1) s += __shfl_down(s, off);
  if ((tid & 63) == 0) s_red[tid >> 6] = s;
  __syncthreads();
  if (tid == 0)
    partial[blockIdx.x] = (float)(s_red[0] + s_red[1] + s_red[2] + s_red[3]);
}

// ---------- final conv-transpose 128 -> 3, write x_recon ----------
__global__ __launch_bounds__(128, 2) void conv_out3(
    const float* __restrict__ in, const float* __restrict__ w,
    const float* __restrict__ bias, float* __restrict__ out) {
  __shared__ float s_in[16][3][130];
  __shared__ float s_w[128][28];  // [ci][tap*3+oc]
  const int tid = threadIdx.x;  // 128
  const int b = blockIdx.x >> 7;
  const int y = blockIdx.x & 127;
  for (int i = tid; i < 128 * 27; i += 128) {
    int ci = i / 27, rem = i % 27, oc = rem / 9, tap = rem % 9;
    int ky = tap / 3, kx = tap % 3;
    s_w[ci][tap * 3 + oc] = w[((ci * 3 + oc) * 3 + (2 - ky)) * 3 + (2 - kx)];
  }
  float acc[3] = {0.f, 0.f, 0.f};
  const int x = tid;
#pragma unroll 1
  for (int ci0 = 0; ci0 < 128; ci0 += 16) {
    for (int i = tid; i < 16 * 390; i += 128) {
      int ci = i / 390;
      int rem = i - ci * 390;
      int r = rem / 130;
      int px = rem - r * 130;
      int yy = y + r - 1;
      float v = 0.f;
      if (yy >= 0 && yy < HH && px >= 1 && px <= 128)
        v = in[((b * 128 + ci0 + ci) * HH + yy) * WW + (px - 1)];
      s_in[ci][r][px] = v;
    }
    __syncthreads();
#pragma unroll 1
    for (int ci = 0; ci < 16; ++ci) {
#pragma unroll
      for (int r = 0; r < 3; ++r) {
        float i3[3] = {s_in[ci][r][x], s_in[ci][r][x + 1], s_in[ci][r][x + 2]};
#pragma unroll
        for (int dx = 0; dx < 3; ++dx)
#pragma unroll
          for (int oc = 0; oc < 3; ++oc)
            acc[oc] += s_w[ci0 + ci][(r * 3 + dx) * 3 + oc] * i3[dx];
      }
    }
    __syncthreads();
  }
#pragma unroll
  for (int oc = 0; oc < 3; ++oc)
    out[((b * 3 + oc) * HH + y) * WW + x] = acc[oc] + bias[oc];
}

// ---------- finalize: loss + perplexity (fp64; runs before decoder) ----------
__global__ void finalize(const float* __restrict__ partial,
                         const int* __restrict__ counts, float* __restrict__ out) {
  __shared__ double redh[4], reds[4];
  const int tid = threadIdx.x;  // 256
  double h = 0.0;
  for (int k = tid; k < KK; k += 256) {
    double p = (double)counts[k] * (1.0 / (double)NPIX);
    h += p * log(p + 1e-10);
  }
  double s = 0.0;
  for (int i = tid; i < VQ_BLOCKS; i += 256) s += (double)partial[i];
  for (int off = 32; off; off >>= 1) {
    h += __shfl_down(h, off);
    s += __shfl_down(s, off);
  }
  if ((tid & 63) == 0) { redh[tid >> 6] = h; reds[tid >> 6] = s; }
  __syncthreads();
  if (tid == 0) {
    double Hs = redh[0] + redh[1] + redh[2] + redh[3];
    double Ss = reds[0] + reds[1] + reds[2] + reds[3];
    out[0] = (float)(0.25 * Ss * (1.0 / (double)NELEM));
    out[1 + XRECON] = (float)exp(-Hs);
  }
}

}  // namespace

extern "C" void kernel_launch(void* const* d_in, const int* in_sizes, int n_in,
                              void* d_out, int out_size, void* d_ws, size_t ws_size,
                              hipStream_t stream) {
  (void)in_sizes; (void)n_in; (void)out_size; (void)ws_size;
  const float* x       = (const float*)d_in[0];
  const float* enc_w0  = (const float*)d_in[1];
  const float* enc_b0  = (const float*)d_in[2];
  const float* enc_wh  = (const float*)d_in[3];
  const float* enc_bh  = (const float*)d_in[4];
  const float* pre_w   = (const float*)d_in[5];
  const float* pre_b   = (const float*)d_in[6];
  const float* codebook= (const float*)d_in[7];
  const float* dec_wh  = (const float*)d_in[8];
  const float* dec_bh  = (const float*)d_in[9];
  const float* dec_wl  = (const float*)d_in[10];
  const float* dec_bl  = (const float*)d_in[11];
  float* out = (float*)d_out;

  // Workspace: exactly two NELEM fp32 activation buffers (256 MiB).
  float* A = (float*)d_ws;
  float* Bf = A + NELEM;
  // Transient scratch in d_out's x_recon region; consumed by finalize()
  // BEFORE the decoder writes d_out (stream-ordered).
  int* counts = (int*)(out + 1);  // 512 ints
  float* partial = out + 1 + KK;  // VQ_BLOCKS floats (8192)

  const int LSTRIDE = 128 * 128 * 9;  // per-layer weight stride
  const int CGRID = NB * HH * 2;      // 4096

  zero_counts<<<1, 256, 0, stream>>>(counts);

  // encoder: layer-1 fp64 acc (cheap); 128->128 layers fp32 acc (r9
  // experiment: faithful fp32 K-sequential sample of the reference cluster)
  conv3x3<3, 3, false, float, float, double><<<CGRID, 256, 0, stream>>>(
      x, enc_w0, enc_b0, A);
  conv3x3<128, 8, false, float, float, float><<<CGRID, 256, 0, stream>>>(
      A, enc_wh, enc_bh, Bf);
  conv3x3<128, 8, false, float, float, float><<<CGRID, 256, 0, stream>>>(
      Bf, enc_wh + LSTRIDE, enc_bh + 128, A);
  conv3x3<128, 8, false, float, float, float><<<CGRID, 256, 0, stream>>>(
      A, enc_wh + 2 * LSTRIDE, enc_bh + 256, Bf);

  // pre-VQ 1x1 -> fp32 NHWC flat in A (fp64 acc, one fp32 rounding)
  prevq_nhwc<<<CGRID, 256, 0, stream>>>(Bf, pre_w, pre_b, A);

  // VQ: fp32 BLAS-order FMA-chain scores (verified correct r7); q -> Bf
  vq_fused<<<VQ_BLOCKS, 256, 0, stream>>>(A, codebook, Bf, partial, counts);

  // loss + perplexity (before decoder overwrites the d_out scratch region)
  finalize<<<1, 256, 0, stream>>>(partial, counts, out);

  // decoder: fp32 acc (noise << bf16 quantum of the check; r2/r7 evidence)
  conv3x3<128, 8, true, float, float, float><<<CGRID, 256, 0, stream>>>(
      Bf, dec_wh, dec_bh, A);
  conv3x3<128, 8, true, float, float, float><<<CGRID, 256, 0, stream>>>(
      A, dec_wh + LSTRIDE, dec_bh + 128, Bf);
  conv3x3<128, 8, true, float, float, float><<<CGRID, 256, 0, stream>>>(
      Bf, dec_wh + 2 * LSTRIDE, dec_bh + 256, A);
  conv_out3<<<NB * HH, 128, 0, stream>>>(A, dec_wl, dec_bl, out + 1);
}

// Round 11
// 8383.089 us; speedup vs baseline: 1.5509x; 1.0881x over previous
//
#include <hip/hip_runtime.h>

namespace {

constexpr int NB = 16, HH = 128, WW = 128, KK = 512, DD = 128;
constexpr int NPIX = NB * HH * WW;        // 262144
constexpr int NELEM = NPIX * DD;          // 33554432
constexpr int XRECON = NB * 3 * HH * WW;  // 786432
constexpr int VQ_BLK_PX = 64;
constexpr int VQ_BLOCKS = NPIX / VQ_BLK_PX;  // 4096

// ---------- zero the code-usage histogram (lives in d_out scratch) ----------
__global__ void zero_counts(int* __restrict__ counts) {
  const int t = threadIdx.x;
  counts[t] = 0;
  counts[t + 256] = 0;
}

// ---------- direct 3x3 conv, stride1 pad1, NCHW ----------
// FMA order per output = ci ascending (CT-invariant), tap-row, tap-col.
// ACC=float for 128->128 convs (faithful fp32 chain, r9-verified);
// ACC=double for layer-1 (r9 numerics). s_in pre-widened; swizzle px+(px>>3).
template <int CIN, int CT, bool TRANS, typename ACC>
__global__ __launch_bounds__(256, 6) void conv3x3(
    const float* __restrict__ in, const float* __restrict__ w,
    const float* __restrict__ bias, float* __restrict__ out) {
  __shared__ __align__(16) ACC s_in[CT][3][74];    // [ci][row][phys(px)]
  __shared__ __align__(16) float s_w[CT * 9][132]; // [ci*9+tap][oc]
  const int tid = threadIdx.x;
  const int b = blockIdx.x >> 8;
  const int y = (blockIdx.x >> 1) & 127;
  const int x0base = (blockIdx.x & 1) << 6;
  const int ocg = tid >> 3;  // 32 groups of 4 oc
  const int pxg = tid & 7;   // 8 groups of 8 px
  const int x0 = pxg * 8;
  const int f0 = pxg * 9;    // swizzled base: px=pxg*8 -> phys=pxg*9

  ACC acc[4][8];
#pragma unroll
  for (int k = 0; k < 4; ++k)
#pragma unroll
    for (int p = 0; p < 8; ++p) acc[k][p] = (ACC)0;

#pragma unroll 1
  for (int ci0 = 0; ci0 < CIN; ci0 += CT) {
    for (int i = tid; i < CT * 198; i += 256) {
      int ci = i / 198;
      int rem = i - ci * 198;
      int r = rem / 66;
      int px = rem - r * 66;
      int yy = y + r - 1;
      int xx = x0base + px - 1;
      float v = 0.f;
      if (yy >= 0 && yy < HH && xx >= 0 && xx < WW)
        v = in[((b * CIN + ci0 + ci) * HH + yy) * WW + xx];
      s_in[ci][r][px + (px >> 3)] = (ACC)v;
    }
    // weights: one float4 (4 consecutive oc) per LDS write
    for (int i = tid; i < 32 * CT * 9; i += 256) {
      int ocg4 = i / (CT * 9);
      int j = i - ocg4 * (CT * 9);
      float4 wv;
      if (!TRANS) {
        const float* wp = w + ci0 * 9 + j;
        wv.x = wp[(ocg4 * 4 + 0) * (CIN * 9)];
        wv.y = wp[(ocg4 * 4 + 1) * (CIN * 9)];
        wv.z = wp[(ocg4 * 4 + 2) * (CIN * 9)];
        wv.w = wp[(ocg4 * 4 + 3) * (CIN * 9)];
      } else {
        int ci = j / 9;
        int tap = j - ci * 9;
        int ky = tap / 3, kx = tap - ky * 3;
        const float* wp = w + ((size_t)(ci0 + ci) * 128) * 9 + (2 - ky) * 3 + (2 - kx);
        wv.x = wp[(ocg4 * 4 + 0) * 9];
        wv.y = wp[(ocg4 * 4 + 1) * 9];
        wv.z = wp[(ocg4 * 4 + 2) * 9];
        wv.w = wp[(ocg4 * 4 + 3) * 9];
      }
      *reinterpret_cast<float4*>(&s_w[j][ocg4 * 4]) = wv;
    }
    __syncthreads();
#pragma unroll 1
    for (int ci = 0; ci < CT; ++ci) {
#pragma unroll
      for (int r = 0; r < 3; ++r) {
        ACC ind[10];
#pragma unroll
        for (int m = 0; m < 8; ++m) ind[m] = s_in[ci][r][f0 + m];
        ind[8] = s_in[ci][r][f0 + 9];   // px = x0+8 -> phys f0+9
        ind[9] = s_in[ci][r][f0 + 10];  // px = x0+9 -> phys f0+10
#pragma unroll
        for (int dx = 0; dx < 3; ++dx) {
          float4 w4 = *reinterpret_cast<const float4*>(&s_w[ci * 9 + r * 3 + dx][ocg * 4]);
          ACC wd[4] = {(ACC)w4.x, (ACC)w4.y, (ACC)w4.z, (ACC)w4.w};
#pragma unroll
          for (int k = 0; k < 4; ++k)
#pragma unroll
            for (int p = 0; p < 8; ++p) acc[k][p] += wd[k] * ind[p + dx];
        }
      }
    }
    __syncthreads();
  }
#pragma unroll
  for (int k = 0; k < 4; ++k) {
    int oc = ocg * 4 + k;
    ACC bv = (ACC)bias[oc];
    float* op = out + ((b * 128 + oc) * HH + y) * WW + x0base + x0;
    float4 v0 = {(float)(acc[k][0] + bv), (float)(acc[k][1] + bv),
                 (float)(acc[k][2] + bv), (float)(acc[k][3] + bv)};
    float4 v1 = {(float)(acc[k][4] + bv), (float)(acc[k][5] + bv),
                 (float)(acc[k][6] + bv), (float)(acc[k][7] + bv)};
    *reinterpret_cast<float4*>(op) = v0;
    *reinterpret_cast<float4*>(op + 4) = v1;
  }
}

// ---------- 1x1 conv (pre-VQ), fp32 NCHW -> fp32 NHWC flat, fp64 acc (r9) ----------
__global__ __launch_bounds__(256, 3) void prevq_nhwc(
    const float* __restrict__ in, const float* __restrict__ wmat,
    const float* __restrict__ bias, float* __restrict__ flat) {
  __shared__ __align__(16) float s_z[32][68];   // [c][px]
  __shared__ __align__(16) float s_w[32][132];  // [c][o]
  const int tid = threadIdx.x;
  const int b = blockIdx.x >> 8;
  const int y = (blockIdx.x >> 1) & 127;
  const int x0base = (blockIdx.x & 1) << 6;
  const int ocg = tid >> 3;  // 32 x 4 oc
  const int pxg = tid & 7;   // 8 x 8 px
  double acc[4][8];
#pragma unroll
  for (int k = 0; k < 4; ++k)
#pragma unroll
    for (int p = 0; p < 8; ++p) acc[k][p] = 0.0;

#pragma unroll 1
  for (int c0 = 0; c0 < 128; c0 += 32) {
    for (int t = tid; t < 32 * 64; t += 256) {
      int c = t >> 6, px = t & 63;
      s_z[c][px] = in[((b * 128 + c0 + c) * HH + y) * WW + x0base + px];
    }
    for (int t = tid; t < 32 * 128; t += 256) {
      int o = t >> 5, c = t & 31;
      s_w[c][o] = wmat[o * 128 + c0 + c];
    }
    __syncthreads();
#pragma unroll 1
    for (int c = 0; c < 32; ++c) {
      double f8[8];
#pragma unroll
      for (int p = 0; p < 8; ++p) f8[p] = (double)s_z[c][pxg * 8 + p];
      float4 w4 = *reinterpret_cast<const float4*>(&s_w[c][ocg * 4]);
      double wd[4] = {(double)w4.x, (double)w4.y, (double)w4.z, (double)w4.w};
#pragma unroll
      for (int k = 0; k < 4; ++k)
#pragma unroll
        for (int p = 0; p < 8; ++p) acc[k][p] += wd[k] * f8[p];
    }
    __syncthreads();
  }
  double bv[4];
#pragma unroll
  for (int k = 0; k < 4; ++k) bv[k] = (double)bias[ocg * 4 + k];
  const int pixbase = (b * HH + y) * WW + x0base + pxg * 8;
#pragma unroll
  for (int p = 0; p < 8; ++p) {
    float* op = flat + (pixbase + p) * DD + ocg * 4;
#pragma unroll
    for (int k = 0; k < 4; ++k) op[k] = (float)(acc[k][p] + bv[k]);
  }
}

// ---------- numpy-faithful fp32 sum of squares over 128 elems ----------
__device__ __forceinline__ float pairwise8_sq(const float* v) {
  float r[8];
#pragma unroll
  for (int j = 0; j < 8; ++j) r[j] = __fmul_rn(v[j], v[j]);
#pragma unroll
  for (int i = 8; i < 128; i += 8)
#pragma unroll
    for (int j = 0; j < 8; ++j) r[j] = __fadd_rn(r[j], __fmul_rn(v[i + j], v[i + j]));
  return __fadd_rn(__fadd_rn(__fadd_rn(r[0], r[1]), __fadd_rn(r[2], r[3])),
                   __fadd_rn(__fadd_rn(r[4], r[5]), __fadd_rn(r[6], r[7])));
}

// ---------- fused VQ, reference-faithful fp32 scoring (DO NOT CHANGE MATH) ----------
// 64 px/block, code tile 64 (16 px-groups x 16 code-groups of 4).
// Per-accumulator FMA chain strictly d-ascending (identical rounding to r7-r9).
constexpr int SF_OFF = 0;                    // float[64][132] = 33792 B
constexpr int SC_OFF = 33792;                // float[64][132] = 33792 B
constexpr int SRB_OFF = SC_OFF;              // float[16][4][17] (aliases s_c, used after)
constexpr int SRI_OFF = SC_OFF + 4352;       // int[16][4][17]
constexpr int SCN_OFF = SC_OFF + 33792;      // float[64] @ 67584
constexpr int SZN_OFF = SCN_OFF + 256;       // float[64]
constexpr int SIDX_OFF = SZN_OFF + 256;      // int[64]
constexpr int SRED_OFF = SIDX_OFF + 256;     // double[4]
constexpr int SMEM_BYTES = SRED_OFF + 32;    // 68384

__global__ __launch_bounds__(256, 2) void vq_fused(
    const float* __restrict__ flat, const float* __restrict__ codebook,
    float* __restrict__ q, float* __restrict__ partial, int* __restrict__ counts) {
  __shared__ __align__(16) char smem[SMEM_BYTES];
  float (*s_f)[132] = reinterpret_cast<float (*)[132]>(smem + SF_OFF);
  float (*s_c)[132] = reinterpret_cast<float (*)[132]>(smem + SC_OFF);
  float (*s_rb)[4][17] = reinterpret_cast<float (*)[4][17]>(smem + SRB_OFF);
  int (*s_ri)[4][17] = reinterpret_cast<int (*)[4][17]>(smem + SRI_OFF);
  float* s_cn = reinterpret_cast<float*>(smem + SCN_OFF);
  float* s_zn = reinterpret_cast<float*>(smem + SZN_OFF);
  int* s_idx = reinterpret_cast<int*>(smem + SIDX_OFF);
  double* s_red = reinterpret_cast<double*>(smem + SRED_OFF);

  const int tid = threadIdx.x;
  const int n0 = blockIdx.x * VQ_BLK_PX;
  const int pxg = tid & 15;  // 16 pixel groups of 4
  const int cg = tid >> 4;   // 16 code groups of 4 (tile of 64 codes)

  for (int t = tid; t < VQ_BLK_PX * 128; t += 256) {
    int i = t >> 7, d = t & 127;
    s_f[i][d] = flat[(n0 + i) * DD + d];
  }
  __syncthreads();
  if (tid < VQ_BLK_PX) s_zn[tid] = pairwise8_sq(&s_f[tid][0]);

  float best[4] = {3.402823466e+38f, 3.402823466e+38f,
                   3.402823466e+38f, 3.402823466e+38f};
  int bi[4] = {0, 0, 0, 0};

#pragma unroll 1
  for (int c0 = 0; c0 < KK; c0 += 64) {
    for (int t = tid; t < 64 * 128; t += 256) {
      int cc = t >> 7, d = t & 127;
      s_c[cc][d] = codebook[(c0 + cc) * DD + d];
    }
    __syncthreads();
    if (tid < 64) s_cn[tid] = pairwise8_sq(&s_c[tid][0]);
    __syncthreads();
    float acc[4][4];
#pragma unroll
    for (int i = 0; i < 4; ++i)
#pragma unroll
      for (int j = 0; j < 4; ++j) acc[i][j] = 0.f;
#pragma unroll 1
    for (int d0 = 0; d0 < 128; d0 += 4) {
      float4 f4[4], c4[4];
#pragma unroll
      for (int i = 0; i < 4; ++i)
        f4[i] = *reinterpret_cast<const float4*>(&s_f[pxg * 4 + i][d0]);
#pragma unroll
      for (int j = 0; j < 4; ++j)
        c4[j] = *reinterpret_cast<const float4*>(&s_c[cg * 4 + j][d0]);
      // d ascending within the quad: chain order identical to scalar loop
#pragma unroll
      for (int i = 0; i < 4; ++i) {
#pragma unroll
        for (int j = 0; j < 4; ++j) {
          acc[i][j] = __fmaf_rn(f4[i].x, c4[j].x, acc[i][j]);
          acc[i][j] = __fmaf_rn(f4[i].y, c4[j].y, acc[i][j]);
          acc[i][j] = __fmaf_rn(f4[i].z, c4[j].z, acc[i][j]);
          acc[i][j] = __fmaf_rn(f4[i].w, c4[j].w, acc[i][j]);
        }
      }
    }
#pragma unroll
    for (int i = 0; i < 4; ++i)
#pragma unroll
      for (int j = 0; j < 4; ++j) {
        float score = __fsub_rn(__fadd_rn(s_zn[pxg * 4 + i], s_cn[cg * 4 + j]),
                                __fmul_rn(2.0f, acc[i][j]));
        int code = c0 + cg * 4 + j;
        if (score < best[i]) { best[i] = score; bi[i] = code; }
      }
    __syncthreads();
  }
  // cross-group reduction (s_rb/s_ri alias the now-dead code tile)
#pragma unroll
  for (int i = 0; i < 4; ++i) {
    s_rb[pxg][i][cg] = best[i];
    s_ri[pxg][i][cg] = bi[i];
  }
  __syncthreads();
  if (tid < 16) {
    for (int i = 0; i < 4; ++i) {
      float m = s_rb[tid][i][0];
      int mi = s_ri[tid][i][0];
      for (int g = 1; g < 16; ++g) {
        float v = s_rb[tid][i][g];
        int vi = s_ri[tid][i][g];
        if (v < m || (v == m && vi < mi)) { m = v; mi = vi; }
      }
      s_idx[tid * 4 + i] = mi;
    }
  }
  __syncthreads();
  if (tid < VQ_BLK_PX) atomicAdd(&counts[s_idx[tid]], 1);

  // gather -> q (fp32 NCHW) + fp64 SSE vs fp32 z (still in s_f)
  const int px = tid & 63;
  const int dg = tid >> 6;  // 4 groups of 32 channels
  const int n = n0 + px;
  const int bl = n >> 14, rem = n & 16383, y = rem >> 7, x = rem & 127;
  const int k = s_idx[px];
  const float* crow = codebook + k * DD + dg * 32;
  float* qb = q + ((bl * 128 + dg * 32) * HH + y) * WW + x;
  double s = 0.0;
#pragma unroll 4
  for (int j = 0; j < 32; ++j) {
    float e = crow[j];
    double dd = (double)e - (double)s_f[px][dg * 32 + j];
    s += dd * dd;
    qb[j * (HH * WW)] = e;
  }
  for (int off = 32; off; off >>= 1) s += __shfl_down(s, off);
  if ((tid & 63) == 0) s_red[tid >> 6] = s;
  __syncthreads();
  if (tid == 0)
    partial[blockIdx.x] = (float)(s_red[0] + s_red[1] + s_red[2] + s_red[3]);
}

// ---------- final conv-transpose 128 -> 3, write x_recon ----------
__global__ __launch_bounds__(128, 2) void conv_out3(
    const float* __restrict__ in, const float* __restrict__ w,
    const float* __restrict__ bias, float* __restrict__ out) {
  __shared__ float s_in[16][3][130];
  __shared__ float s_w[128][28];  // [ci][tap*3+oc]
  const int tid = threadIdx.x;  // 128
  const int b = blockIdx.x >> 7;
  const int y = blockIdx.x & 127;
  for (int i = tid; i < 128 * 27; i += 128) {
    int ci = i / 27, rem = i % 27, oc = rem / 9, tap = rem % 9;
    int ky = tap / 3, kx = tap % 3;
    s_w[ci][tap * 3 + oc] = w[((ci * 3 + oc) * 3 + (2 - ky)) * 3 + (2 - kx)];
  }
  float acc[3] = {0.f, 0.f, 0.f};
  const int x = tid;
#pragma unroll 1
  for (int ci0 = 0; ci0 < 128; ci0 += 16) {
    for (int i = tid; i < 16 * 390; i += 128) {
      int ci = i / 390;
      int rem = i - ci * 390;
      int r = rem / 130;
      int px = rem - r * 130;
      int yy = y + r - 1;
      float v = 0.f;
      if (yy >= 0 && yy < HH && px >= 1 && px <= 128)
        v = in[((b * 128 + ci0 + ci) * HH + yy) * WW + (px - 1)];
      s_in[ci][r][px] = v;
    }
    __syncthreads();
#pragma unroll 1
    for (int ci = 0; ci < 16; ++ci) {
#pragma unroll
      for (int r = 0; r < 3; ++r) {
        float i3[3] = {s_in[ci][r][x], s_in[ci][r][x + 1], s_in[ci][r][x + 2]};
#pragma unroll
        for (int dx = 0; dx < 3; ++dx)
#pragma unroll
          for (int oc = 0; oc < 3; ++oc)
            acc[oc] += s_w[ci0 + ci][(r * 3 + dx) * 3 + oc] * i3[dx];
      }
    }
    __syncthreads();
  }
#pragma unroll
  for (int oc = 0; oc < 3; ++oc)
    out[((b * 3 + oc) * HH + y) * WW + x] = acc[oc] + bias[oc];
}

// ---------- finalize: loss + perplexity (fp64; runs before decoder) ----------
__global__ void finalize(const float* __restrict__ partial,
                         const int* __restrict__ counts, float* __restrict__ out) {
  __shared__ double redh[4], reds[4];
  const int tid = threadIdx.x;  // 256
  double h = 0.0;
  for (int k = tid; k < KK; k += 256) {
    double p = (double)counts[k] * (1.0 / (double)NPIX);
    h += p * log(p + 1e-10);
  }
  double s = 0.0;
  for (int i = tid; i < VQ_BLOCKS; i += 256) s += (double)partial[i];
  for (int off = 32; off; off >>= 1) {
    h += __shfl_down(h, off);
    s += __shfl_down(s, off);
  }
  if ((tid & 63) == 0) { redh[tid >> 6] = h; reds[tid >> 6] = s; }
  __syncthreads();
  if (tid == 0) {
    double Hs = redh[0] + redh[1] + redh[2] + redh[3];
    double Ss = reds[0] + reds[1] + reds[2] + reds[3];
    out[0] = (float)(0.25 * Ss * (1.0 / (double)NELEM));
    out[1 + XRECON] = (float)exp(-Hs);
  }
}

}  // namespace

extern "C" void kernel_launch(void* const* d_in, const int* in_sizes, int n_in,
                              void* d_out, int out_size, void* d_ws, size_t ws_size,
                              hipStream_t stream) {
  (void)in_sizes; (void)n_in; (void)out_size; (void)ws_size;
  const float* x       = (const float*)d_in[0];
  const float* enc_w0  = (const float*)d_in[1];
  const float* enc_b0  = (const float*)d_in[2];
  const float* enc_wh  = (const float*)d_in[3];
  const float* enc_bh  = (const float*)d_in[4];
  const float* pre_w   = (const float*)d_in[5];
  const float* pre_b   = (const float*)d_in[6];
  const float* codebook= (const float*)d_in[7];
  const float* dec_wh  = (const float*)d_in[8];
  const float* dec_bh  = (const float*)d_in[9];
  const float* dec_wl  = (const float*)d_in[10];
  const float* dec_bl  = (const float*)d_in[11];
  float* out = (float*)d_out;

  // Workspace: exactly two NELEM fp32 activation buffers (256 MiB).
  float* A = (float*)d_ws;
  float* Bf = A + NELEM;
  // Transient scratch in d_out's x_recon region; consumed by finalize()
  // BEFORE the decoder writes d_out (stream-ordered).
  int* counts = (int*)(out + 1);  // 512 ints
  float* partial = out + 1 + KK;  // VQ_BLOCKS floats (4096)

  const int LSTRIDE = 128 * 128 * 9;  // per-layer weight stride
  const int CGRID = NB * HH * 2;      // 4096

  zero_counts<<<1, 256, 0, stream>>>(counts);

  // encoder: layer-1 fp64 acc, 128-convs fp32 chain acc (r9-proven numerics)
  conv3x3<3, 3, false, double><<<CGRID, 256, 0, stream>>>(x, enc_w0, enc_b0, A);
  conv3x3<128, 4, false, float><<<CGRID, 256, 0, stream>>>(A, enc_wh, enc_bh, Bf);
  conv3x3<128, 4, false, float><<<CGRID, 256, 0, stream>>>(
      Bf, enc_wh + LSTRIDE, enc_bh + 128, A);
  conv3x3<128, 4, false, float><<<CGRID, 256, 0, stream>>>(
      A, enc_wh + 2 * LSTRIDE, enc_bh + 256, Bf);

  // pre-VQ 1x1 -> fp32 NHWC flat in A (fp64 acc, r9-proven)
  prevq_nhwc<<<CGRID, 256, 0, stream>>>(Bf, pre_w, pre_b, A);

  // VQ: fp32 BLAS-order FMA-chain scores (locked since r7); q -> Bf
  vq_fused<<<VQ_BLOCKS, 256, 0, stream>>>(A, codebook, Bf, partial, counts);

  // loss + perplexity (before decoder overwrites the d_out scratch region)
  finalize<<<1, 256, 0, stream>>>(partial, counts, out);

  // decoder: fp32 acc (r2/r7-r9 evidence)
  conv3x3<128, 4, true, float><<<CGRID, 256, 0, stream>>>(Bf, dec_wh, dec_bh, A);
  conv3x3<128, 4, true, float><<<CGRID, 256, 0, stream>>>(
      A, dec_wh + LSTRIDE, dec_bh + 128, Bf);
  conv3x3<128, 4, true, float><<<CGRID, 256, 0, stream>>>(
      Bf, dec_wh + 2 * LSTRIDE, dec_bh + 256, A);
  conv_out3<<<NB * HH, 128, 0, stream>>>(A, dec_wl, dec_bl, out + 1);
}